// Round 8
// baseline (154.757 us; speedup 1.0000x reference)
//
#include <hip/hip_runtime.h>
#include <hip/hip_fp16.h>

// fePAM: per-pixel gather attention. Shapes fixed by setup_inputs().
// Structure: fused scores+values (R7) + grid-wide phase alignment:
// all 2048 blocks co-resident (lb 256,8) + inter-phase barrier, so only ONE
// 4.19 MB gather table is hot per XCD at a time (R7 showed 131.7 MB HBM
// re-fetch from having both St and Rt hot simultaneously).
constexpr int B = 2, C = 64, H = 128, W = 256, N = H * W, K = 32;

typedef _Float16 hf2 __attribute__((ext_vector_type(2)));

// DPP helper (VALU-pipe cross-lane)
template <int CTRL>
__device__ __forceinline__ float dppf(float x) {
    int i = __builtin_bit_cast(int, x);
    int r = __builtin_amdgcn_update_dpp(i, i, CTRL, 0xF, 0xF, false);
    return __builtin_bit_cast(float, r);
}
// 0xB1 quad_perm xor1 | 0x4E quad_perm xor2 | 0x141 row_half_mirror (xor4)
// 0x128 row_ror:8 == xor8 within a 16-lane row

__device__ __forceinline__ unsigned sel4(const ushort4& v, int g) {
    return g == 0 ? v.x : g == 1 ? v.y : g == 2 ? v.z : v.w;
}

// ---------------------------------------------------------------------------
// Prep: z=0/1/2 transpose+fp16 S,R,Q: [B][C][N] -> [B][N][C].
// z=3 (b==0 only): pack idx16[n][slot]=px*W+py, slot=(k&7)*4+(k>>3).
// grid = (N/64, B, 4), block = 256.   [verbatim R0]
// ---------------------------------------------------------------------------
__global__ __launch_bounds__(256) void fepam_prep(
    const float* __restrict__ Q, const float* __restrict__ S,
    const float* __restrict__ R,
    const int* __restrict__ Px, const int* __restrict__ Py,
    __half* __restrict__ Qt, __half* __restrict__ St, __half* __restrict__ Rt,
    unsigned short* __restrict__ Idx) {
    const int n0 = blockIdx.x * 64;
    const int b  = blockIdx.y;
    const int z  = blockIdx.z;

    if (z == 3) {
        if (b) return;
#pragma unroll
        for (int t = 0; t < 8; ++t) {
            const int e  = threadIdx.x + 256 * t;   // 0..2047
            const int nl = e >> 5, k = e & 31;
            const int n  = n0 + nl;
            const int idx = Px[(size_t)n * K + k] * W + Py[(size_t)n * K + k];
            Idx[(size_t)n * K + (k & 7) * 4 + (k >> 3)] = (unsigned short)idx;
        }
        return;
    }

    __shared__ float tile[C][65];
    const float* src = (z == 0 ? S : (z == 1 ? R : Q)) + (size_t)b * C * N;
    __half2* d2 = (__half2*)((z == 0 ? St : (z == 1 ? Rt : Qt)) +
                             (size_t)b * N * C);
    {
        const int j = threadIdx.x & 63, c0 = threadIdx.x >> 6;
        const float* s = src + n0 + j;
#pragma unroll
        for (int r = 0; r < 16; ++r) {
            int c = c0 + r * 4;
            tile[c][j] = s[(size_t)c * N];  // coalesced 256B along n
        }
    }
    __syncthreads();
    {
        const int c2 = threadIdx.x & 31, j0 = threadIdx.x >> 5;
#pragma unroll
        for (int r = 0; r < 8; ++r) {
            int j = j0 + 8 * r;
            d2[(size_t)(n0 + j) * 32 + c2] =
                __floats2half2_rn(tile[2 * c2][j], tile[2 * c2 + 1][j]);
        }
    }
}

// ---------------------------------------------------------------------------
// Fused attention, phase-aligned: phase 1 gathers K rows from St (4.19 MB
// table, batch-pinned per XCD via bx&1), softmax -> weights in LDS; barrier;
// phase 2 gathers V rows from Rt. Grid = 2048 = ALL blocks co-resident at
// 8 blocks/CU, so every block transitions phases within ~1 us -> one table
// hot at a time. block = 256 (4 waves; 1 wave = 8 pixels). LDS 12.5 KB.
// ---------------------------------------------------------------------------
__global__ __launch_bounds__(256, 8) void fepam_attn(
    const __half* __restrict__ Qt, const unsigned short* __restrict__ Idx,
    const __half* __restrict__ St, const __half* __restrict__ Rt,
    float* __restrict__ Out) {
    __shared__ __align__(16) float aw[32][32];  // 4 KB: weights, wave-private
    __shared__ __align__(16) float ot[32][66];  // 8.4 KB: output transpose

    const int tid  = threadIdx.x;
    const int lane = tid & 63;
    const int wave = tid >> 6;        // 0..3
    const int bx   = blockIdx.x;
    const int b    = bx & 1;          // XCD batch-parity swizzle
    const int n0t  = (bx >> 1) * 32;
    const int n0   = n0t + wave * 8;

    const int c_oct = lane & 7;
    const int k_loc = lane >> 3;

    const __half* Qtb = Qt + (size_t)b * N * C;
    const __half* Stb = St + (size_t)b * N * C;
    const __half* Rtb = Rt + (size_t)b * N * C;

    auto ldi = [&](int p) {
        return *(const ushort4*)(Idx + (size_t)(n0 + p) * K + k_loc * 4);
    };

    // ===================== phase 1: scores (verbatim R0) ===================
    {
        auto ldq = [&](int p) {
            return *(const float4*)(Qtb + (size_t)(n0 + p) * C + c_oct * 8);
        };
        auto ldk = [&](const ushort4& iv, int g) {
            return *(const float4*)(Stb + ((size_t)sel4(iv, g) << 6) +
                                    c_oct * 8);
        };

        ushort4 iv_c = ldi(0), iv_n = ldi(1);
        float4  q_c  = ldq(0), q_n  = ldq(1);
        float4  k_c[4];
#pragma unroll
        for (int g = 0; g < 4; ++g) k_c[g] = ldk(iv_c, g);

#pragma unroll
        for (int p = 0; p < 8; ++p) {
            // prefetch: keys for p+1, iv/q for p+2
            float4 k_n[4];
            if (p < 7) {
#pragma unroll
                for (int g = 0; g < 4; ++g) k_n[g] = ldk(iv_n, g);
            }
            ushort4 iv_2;
            float4  q_2;
            if (p < 6) { iv_2 = ldi(p + 2); q_2 = ldq(p + 2); }

            // ---- compute pixel p
            float s[4];
#pragma unroll
            for (int g = 0; g < 4; ++g) {
                const hf2* k2 = (const hf2*)&k_c[g];
                const hf2* q2 = (const hf2*)&q_c;
                float acc = 0.f;
#pragma unroll
                for (int u = 0; u < 4; ++u)
                    acc = __builtin_amdgcn_fdot2(k2[u], q2[u], acc, false);
                s[g] = acc;
            }
#pragma unroll
            for (int g = 0; g < 4; ++g) {  // reduce over c_oct: pure DPP
                s[g] += dppf<0xB1>(s[g]);
                s[g] += dppf<0x4E>(s[g]);
                s[g] += dppf<0x141>(s[g]);
            }
            float m = fmaxf(fmaxf(s[0], s[1]), fmaxf(s[2], s[3]));
            m = fmaxf(m, dppf<0x128>(m));
            m = fmaxf(m, __shfl_xor(m, 16));
            m = fmaxf(m, __shfl_xor(m, 32));
            float e0 = __expf(s[0] - m), e1 = __expf(s[1] - m);
            float e2 = __expf(s[2] - m), e3 = __expf(s[3] - m);
            float l = (e0 + e1) + (e2 + e3);
            l += dppf<0x128>(l);
            l += __shfl_xor(l, 16);
            l += __shfl_xor(l, 32);
            const float inv = 1.0f / l;

            if (c_oct == 0) {  // 8 lanes x 16B, wave-private LDS row
                *(float4*)&aw[wave * 8 + p][k_loc * 4] =
                    make_float4(e0 * inv, e1 * inv, e2 * inv, e3 * inv);
            }

            // ---- shift pipeline
#pragma unroll
            for (int g = 0; g < 4; ++g) k_c[g] = k_n[g];
            iv_c = iv_n; q_c = q_n;
            iv_n = iv_2; q_n = q_2;
        }
    }

    // Phase barrier: aligns all 4 waves so St -> Rt transition is sharp.
    __syncthreads();

    // ===================== phase 2: values (verbatim R0) ===================
    {
        const bool hi8  = (lane & 8)  != 0;
        const bool hi16 = (lane & 16) != 0;
        const bool hi32 = (lane & 32) != 0;

        auto ldv = [&](const ushort4& iv, int g) {
            return *(const float4*)(Rtb + ((size_t)sel4(iv, g) << 6) +
                                    c_oct * 8);
        };

        ushort4 i_c = ldi(0), i_n = ldi(1);
        float4  v_c[4];
#pragma unroll
        for (int g = 0; g < 4; ++g) v_c[g] = ldv(i_c, g);

#pragma unroll
        for (int p = 0; p < 8; ++p) {
            float4 v_n[4];
            if (p < 7) {
#pragma unroll
                for (int g = 0; g < 4; ++g) v_n[g] = ldv(i_n, g);
            }
            ushort4 i_2;
            if (p < 6) i_2 = ldi(p + 2);

            // ---- compute pixel p (weights from LDS stash)
            const float4 af = *(const float4*)&aw[wave * 8 + p][k_loc * 4];
            const float a[4] = {af.x, af.y, af.z, af.w};
            float acc[8] = {0, 0, 0, 0, 0, 0, 0, 0};
#pragma unroll
            for (int g = 0; g < 4; ++g) {
                const __half2* v2 = (const __half2*)&v_c[g];
#pragma unroll
                for (int u = 0; u < 4; ++u) {
                    const float2 vf = __half22float2(v2[u]);
                    acc[2 * u]     = fmaf(a[g], vf.x, acc[2 * u]);
                    acc[2 * u + 1] = fmaf(a[g], vf.y, acc[2 * u + 1]);
                }
            }

            // reduce acc[8] over k_loc (xor 8,16,32) with payload halving
            float r4[4];
#pragma unroll
            for (int i = 0; i < 4; ++i) {
                const float send = hi8 ? acc[i] : acc[4 + i];
                const float recv = dppf<0x128>(send);
                r4[i] = (hi8 ? acc[4 + i] : acc[i]) + recv;
            }
            float r2[2];
#pragma unroll
            for (int i = 0; i < 2; ++i) {
                const float send = hi16 ? r4[i] : r4[2 + i];
                const float recv = __shfl_xor(send, 16);
                r2[i] = (hi16 ? r4[2 + i] : r4[i]) + recv;
            }
            {
                const float send = hi32 ? r2[0] : r2[1];
                const float recv = __shfl_xor(send, 32);
                const float r1   = (hi32 ? r2[1] : r2[0]) + recv;
                const int c = c_oct * 8 + (hi8 ? 4 : 0) + (hi16 ? 2 : 0) +
                              (hi32 ? 1 : 0);
                ot[wave * 8 + p][c] = r1;
            }

            // ---- shift pipeline
#pragma unroll
            for (int g = 0; g < 4; ++g) v_c[g] = v_n[g];
            i_c = i_n;
            i_n = i_2;
        }
    }
    __syncthreads();

    // store: ot[j][c] -> Out[b][c][n0t+j] (two 128B segments per instr)
    {
        const int j = tid & 31, c0 = tid >> 5;
        float* od = Out + (size_t)b * C * N + n0t + j;
#pragma unroll
        for (int r = 0; r < 8; ++r) {
            int c = c0 + r * 8;
            od[(size_t)c * N] = ot[j][c];
        }
    }
}

// ---------------------------------------------------------------------------
extern "C" void kernel_launch(void* const* d_in, const int* in_sizes, int n_in,
                              void* d_out, int out_size, void* d_ws, size_t ws_size,
                              hipStream_t stream) {
    const float* Q  = (const float*)d_in[0];
    const float* S  = (const float*)d_in[1];
    const float* R  = (const float*)d_in[2];
    const int*   Px = (const int*)d_in[3];
    const int*   Py = (const int*)d_in[4];
    float* Out = (float*)d_out;

    // ws: St, Rt, Qt (8.39 MB each) + Idx (2.1 MB)
    __half* St = (__half*)d_ws;
    __half* Rt = St + (size_t)B * N * C;
    __half* Qt = Rt + (size_t)B * N * C;
    unsigned short* Idx = (unsigned short*)(Qt + (size_t)B * N * C);

    dim3 pgrid(N / 64, B, 4);
    fepam_prep<<<pgrid, 256, 0, stream>>>(Q, S, R, Px, Py, Qt, St, Rt, Idx);

    dim3 ggrid(N / 32 * B);
    fepam_attn<<<ggrid, 256, 0, stream>>>(Qt, Idx, St, Rt, Out);
}

// Round 9
// 135.973 us; speedup vs baseline: 1.1381x; 1.1381x over previous
//
#include <hip/hip_runtime.h>
#include <hip/hip_fp16.h>

// fePAM: per-pixel gather attention. Shapes fixed by setup_inputs().
// Structure: verified R0 baseline (136 us), with the scores->values
// intermediate slimmed to fp16 weights only (AW, 4.2 MB) instead of packed
// (idx|weight) u32 (16.8 MB); values re-reads Idx. Patterns from verified R3.
constexpr int B = 2, C = 64, H = 128, W = 256, N = H * W, K = 32;

typedef _Float16 hf2 __attribute__((ext_vector_type(2)));

// DPP helper (VALU-pipe cross-lane)
template <int CTRL>
__device__ __forceinline__ float dppf(float x) {
    int i = __builtin_bit_cast(int, x);
    int r = __builtin_amdgcn_update_dpp(i, i, CTRL, 0xF, 0xF, false);
    return __builtin_bit_cast(float, r);
}
// 0xB1 quad_perm xor1 | 0x4E quad_perm xor2 | 0x141 row_half_mirror (xor4)
// 0x128 row_ror:8 == xor8 within a 16-lane row

__device__ __forceinline__ unsigned sel4(const ushort4& v, int g) {
    return g == 0 ? v.x : g == 1 ? v.y : g == 2 ? v.z : v.w;
}

// ---------------------------------------------------------------------------
// Prep: z=0/1/2 transpose+fp16 S,R,Q: [B][C][N] -> [B][N][C].
// z=3 (b==0 only): pack idx16[n][slot]=px*W+py, slot=(k&7)*4+(k>>3).
// grid = (N/64, B, 4), block = 256.   [verbatim R0]
// ---------------------------------------------------------------------------
__global__ __launch_bounds__(256) void fepam_prep(
    const float* __restrict__ Q, const float* __restrict__ S,
    const float* __restrict__ R,
    const int* __restrict__ Px, const int* __restrict__ Py,
    __half* __restrict__ Qt, __half* __restrict__ St, __half* __restrict__ Rt,
    unsigned short* __restrict__ Idx) {
    const int n0 = blockIdx.x * 64;
    const int b  = blockIdx.y;
    const int z  = blockIdx.z;

    if (z == 3) {
        if (b) return;
#pragma unroll
        for (int t = 0; t < 8; ++t) {
            const int e  = threadIdx.x + 256 * t;   // 0..2047
            const int nl = e >> 5, k = e & 31;
            const int n  = n0 + nl;
            const int idx = Px[(size_t)n * K + k] * W + Py[(size_t)n * K + k];
            Idx[(size_t)n * K + (k & 7) * 4 + (k >> 3)] = (unsigned short)idx;
        }
        return;
    }

    __shared__ float tile[C][65];
    const float* src = (z == 0 ? S : (z == 1 ? R : Q)) + (size_t)b * C * N;
    __half2* d2 = (__half2*)((z == 0 ? St : (z == 1 ? Rt : Qt)) +
                             (size_t)b * N * C);
    {
        const int j = threadIdx.x & 63, c0 = threadIdx.x >> 6;
        const float* s = src + n0 + j;
#pragma unroll
        for (int r = 0; r < 16; ++r) {
            int c = c0 + r * 4;
            tile[c][j] = s[(size_t)c * N];  // coalesced 256B along n
        }
    }
    __syncthreads();
    {
        const int c2 = threadIdx.x & 31, j0 = threadIdx.x >> 5;
#pragma unroll
        for (int r = 0; r < 8; ++r) {
            int j = j0 + 8 * r;
            d2[(size_t)(n0 + j) * 32 + c2] =
                __floats2half2_rn(tile[2 * c2][j], tile[2 * c2 + 1][j]);
        }
    }
}

// ---------------------------------------------------------------------------
// Scores: touches ONLY St (4.19 MB/batch, batch-pinned per XCD via bx&1).
// grid = (N/32 * B), block = 256 (4 waves; 1 wave = 8 pixels). No LDS.
// Software-pipelined: iv/q loaded 2 pixels ahead, keys 1 pixel ahead.
// Writes fp16 softmax weights to AW[b][n][k_loc*4+g] (64 B/pixel).
// ---------------------------------------------------------------------------
__global__ __launch_bounds__(256, 6) void fepam_scores(
    const __half* __restrict__ Qt, const unsigned short* __restrict__ Idx,
    const __half* __restrict__ St, __half* __restrict__ AW) {
    const int tid  = threadIdx.x;
    const int lane = tid & 63;
    const int wave = tid >> 6;        // 0..3
    const int bx   = blockIdx.x;
    const int b    = bx & 1;          // XCD batch-parity swizzle
    const int n0   = (bx >> 1) * 32 + wave * 8;

    const int c_oct = lane & 7;
    const int k_loc = lane >> 3;

    const __half* Qtb = Qt + (size_t)b * N * C;
    const __half* Stb = St + (size_t)b * N * C;
    __half* AWb = AW + (size_t)b * N * K;

    auto ldi = [&](int p) {
        return *(const ushort4*)(Idx + (size_t)(n0 + p) * K + k_loc * 4);
    };
    auto ldq = [&](int p) {
        return *(const float4*)(Qtb + (size_t)(n0 + p) * C + c_oct * 8);
    };
    auto ldk = [&](const ushort4& iv, int g) {
        return *(const float4*)(Stb + ((size_t)sel4(iv, g) << 6) + c_oct * 8);
    };

    ushort4 iv_c = ldi(0), iv_n = ldi(1);
    float4  q_c  = ldq(0), q_n  = ldq(1);
    float4  k_c[4];
#pragma unroll
    for (int g = 0; g < 4; ++g) k_c[g] = ldk(iv_c, g);

#pragma unroll
    for (int p = 0; p < 8; ++p) {
        // prefetch: keys for p+1, iv/q for p+2
        float4 k_n[4];
        if (p < 7) {
#pragma unroll
            for (int g = 0; g < 4; ++g) k_n[g] = ldk(iv_n, g);
        }
        ushort4 iv_2;
        float4  q_2;
        if (p < 6) { iv_2 = ldi(p + 2); q_2 = ldq(p + 2); }

        // ---- compute pixel p
        float s[4];
#pragma unroll
        for (int g = 0; g < 4; ++g) {
            const hf2* k2 = (const hf2*)&k_c[g];
            const hf2* q2 = (const hf2*)&q_c;
            float acc = 0.f;
#pragma unroll
            for (int u = 0; u < 4; ++u)
                acc = __builtin_amdgcn_fdot2(k2[u], q2[u], acc, false);
            s[g] = acc;
        }
#pragma unroll
        for (int g = 0; g < 4; ++g) {  // reduce over c_oct: pure DPP
            s[g] += dppf<0xB1>(s[g]);
            s[g] += dppf<0x4E>(s[g]);
            s[g] += dppf<0x141>(s[g]);
        }
        float m = fmaxf(fmaxf(s[0], s[1]), fmaxf(s[2], s[3]));
        m = fmaxf(m, dppf<0x128>(m));
        m = fmaxf(m, __shfl_xor(m, 16));
        m = fmaxf(m, __shfl_xor(m, 32));
        float e0 = __expf(s[0] - m), e1 = __expf(s[1] - m);
        float e2 = __expf(s[2] - m), e3 = __expf(s[3] - m);
        float l = (e0 + e1) + (e2 + e3);
        l += dppf<0x128>(l);
        l += __shfl_xor(l, 16);
        l += __shfl_xor(l, 32);
        const float inv = 1.0f / l;

        if (c_oct == 0) {  // 8 lanes x 8B = contiguous 64B per pixel
            ushort4 hv;
            hv.x = __half_as_ushort(__float2half_rn(e0 * inv));
            hv.y = __half_as_ushort(__float2half_rn(e1 * inv));
            hv.z = __half_as_ushort(__float2half_rn(e2 * inv));
            hv.w = __half_as_ushort(__float2half_rn(e3 * inv));
            *(ushort4*)(AWb + (size_t)(n0 + p) * K + k_loc * 4) = hv;
        }

        // ---- shift pipeline
#pragma unroll
        for (int g = 0; g < 4; ++g) k_c[g] = k_n[g];
        iv_c = iv_n; q_c = q_n;
        iv_n = iv_2; q_n = q_2;
    }
}

// ---------------------------------------------------------------------------
// Values: touches ONLY Rt (4.19 MB/batch, batch-pinned). Streams Idx + AW.
// grid = (N/32 * B), block = 256 (4 waves; 1 wave = 8 pixels). LDS 8.4 KB.
// Software-pipelined like fepam_scores.
// ---------------------------------------------------------------------------
__global__ __launch_bounds__(256, 6) void fepam_values(
    const unsigned short* __restrict__ Idx, const __half* __restrict__ AW,
    const __half* __restrict__ Rt, float* __restrict__ Out) {
    __shared__ __align__(16) float ot[32][66];  // 8.4 KB

    const int tid  = threadIdx.x;
    const int lane = tid & 63;
    const int wave = tid >> 6;        // 0..3
    const int bx   = blockIdx.x;
    const int b    = bx & 1;
    const int n0t  = (bx >> 1) * 32;
    const int n0   = n0t + wave * 8;

    const int c_oct = lane & 7;
    const int k_loc = lane >> 3;
    const bool hi8  = (lane & 8)  != 0;
    const bool hi16 = (lane & 16) != 0;
    const bool hi32 = (lane & 32) != 0;

    const __half* Rtb = Rt + (size_t)b * N * C;
    const __half* AWb = AW + (size_t)b * N * K;

    auto ldi = [&](int p) {
        return *(const ushort4*)(Idx + (size_t)(n0 + p) * K + k_loc * 4);
    };
    auto lda = [&](int p) {
        return *(const ushort4*)(AWb + (size_t)(n0 + p) * K + k_loc * 4);
    };
    auto ldv = [&](const ushort4& iv, int g) {
        return *(const float4*)(Rtb + ((size_t)sel4(iv, g) << 6) + c_oct * 8);
    };

    ushort4 i_c = ldi(0), i_n = ldi(1);
    ushort4 a_c = lda(0), a_n = lda(1);
    float4  v_c[4];
#pragma unroll
    for (int g = 0; g < 4; ++g) v_c[g] = ldv(i_c, g);

#pragma unroll
    for (int p = 0; p < 8; ++p) {
        float4 v_n[4];
        if (p < 7) {
#pragma unroll
            for (int g = 0; g < 4; ++g) v_n[g] = ldv(i_n, g);
        }
        ushort4 i_2, a_2;
        if (p < 6) { i_2 = ldi(p + 2); a_2 = lda(p + 2); }

        // ---- compute pixel p
        const float a[4] = {
            __half2float(__ushort_as_half(a_c.x)),
            __half2float(__ushort_as_half(a_c.y)),
            __half2float(__ushort_as_half(a_c.z)),
            __half2float(__ushort_as_half(a_c.w))};
        float acc[8] = {0, 0, 0, 0, 0, 0, 0, 0};
#pragma unroll
        for (int g = 0; g < 4; ++g) {
            const __half2* v2 = (const __half2*)&v_c[g];
#pragma unroll
            for (int u = 0; u < 4; ++u) {
                const float2 vf = __half22float2(v2[u]);
                acc[2 * u]     = fmaf(a[g], vf.x, acc[2 * u]);
                acc[2 * u + 1] = fmaf(a[g], vf.y, acc[2 * u + 1]);
            }
        }

        // reduce acc[8] over k_loc (xor 8,16,32) with payload halving
        float r4[4];
#pragma unroll
        for (int i = 0; i < 4; ++i) {
            const float send = hi8 ? acc[i] : acc[4 + i];
            const float recv = dppf<0x128>(send);
            r4[i] = (hi8 ? acc[4 + i] : acc[i]) + recv;
        }
        float r2[2];
#pragma unroll
        for (int i = 0; i < 2; ++i) {
            const float send = hi16 ? r4[i] : r4[2 + i];
            const float recv = __shfl_xor(send, 16);
            r2[i] = (hi16 ? r4[2 + i] : r4[i]) + recv;
        }
        {
            const float send = hi32 ? r2[0] : r2[1];
            const float recv = __shfl_xor(send, 32);
            const float r1   = (hi32 ? r2[1] : r2[0]) + recv;
            const int c = c_oct * 8 + (hi8 ? 4 : 0) + (hi16 ? 2 : 0) + (hi32 ? 1 : 0);
            ot[wave * 8 + p][c] = r1;
        }

        // ---- shift pipeline
#pragma unroll
        for (int g = 0; g < 4; ++g) v_c[g] = v_n[g];
        i_c = i_n; a_c = a_n;
        i_n = i_2; a_n = a_2;
    }
    __syncthreads();

    // store: ot[j][c] -> Out[b][c][n0t+j] (two 128B segments per instr)
    {
        const int j = tid & 31, c0 = tid >> 5;
        float* od = Out + (size_t)b * C * N + n0t + j;
#pragma unroll
        for (int r = 0; r < 8; ++r) {
            int c = c0 + r * 8;
            od[(size_t)c * N] = ot[j][c];
        }
    }
}

// ---------------------------------------------------------------------------
extern "C" void kernel_launch(void* const* d_in, const int* in_sizes, int n_in,
                              void* d_out, int out_size, void* d_ws, size_t ws_size,
                              hipStream_t stream) {
    const float* Q  = (const float*)d_in[0];
    const float* S  = (const float*)d_in[1];
    const float* R  = (const float*)d_in[2];
    const int*   Px = (const int*)d_in[3];
    const int*   Py = (const int*)d_in[4];
    float* Out = (float*)d_out;

    // ws: St, Rt, Qt (8.39 MB each) + Idx (2.1 MB) + AW fp16 (4.19 MB)
    __half* St = (__half*)d_ws;
    __half* Rt = St + (size_t)B * N * C;
    __half* Qt = Rt + (size_t)B * N * C;
    unsigned short* Idx = (unsigned short*)(Qt + (size_t)B * N * C);
    __half* AW = (__half*)(Idx + (size_t)N * K);

    dim3 pgrid(N / 64, B, 4);
    fepam_prep<<<pgrid, 256, 0, stream>>>(Q, S, R, Px, Py, Qt, St, Rt, Idx);

    dim3 ggrid(N / 32 * B);
    fepam_scores<<<ggrid, 256, 0, stream>>>(Qt, Idx, St, AW);
    fepam_values<<<ggrid, 256, 0, stream>>>(Idx, AW, Rt, Out);
}